// Round 1
// baseline (450.071 us; speedup 1.0000x reference)
//
#include <hip/hip_runtime.h>
#include <hip/hip_bf16.h>
#include <cstdint>

#define HIDDEN 1024
#define HEADS 16
#define HDIM 64
#define BATCH 4
#define SEQ 2048
#define MTOT (BATCH * SEQ)   // 8192

typedef __attribute__((ext_vector_type(8))) short bfrag;   // 8 bf16 (A/B frag)
typedef __attribute__((ext_vector_type(4))) float cfrag;   // 4 f32 (C/D frag)
typedef __attribute__((ext_vector_type(4))) float float4v;

#define AS1 __attribute__((address_space(1)))
#define AS3 __attribute__((address_space(3)))

__device__ __forceinline__ void gl_lds16(const void* g, void* l) {
  // async global->LDS, 16B per lane; LDS dest = wave-uniform base + lane*16
  __builtin_amdgcn_global_load_lds((AS1 void*)g, (AS3 void*)l, 16, 0, 0);
}

__device__ __forceinline__ uint16_t f2b(float f) {  // f32 -> bf16 bits, RNE
  union { float f; uint32_t u; } v; v.f = f;
  uint32_t u = v.u;
  return (uint16_t)((u + 0x7FFFu + ((u >> 16) & 1u)) >> 16);
}

// ---------------- kernel 1: x fp32 -> bf16 ----------------
__global__ __launch_bounds__(256) void cvt_x_kernel(const float* __restrict__ in,
                                                    uint16_t* __restrict__ out, int n8) {
  int i = blockIdx.x * blockDim.x + threadIdx.x;
  if (i >= n8) return;
  float4v a = ((const float4v*)in)[2 * i];
  float4v b = ((const float4v*)in)[2 * i + 1];
  bfrag o;
  o[0] = (short)f2b(a[0]); o[1] = (short)f2b(a[1]);
  o[2] = (short)f2b(a[2]); o[3] = (short)f2b(a[3]);
  o[4] = (short)f2b(b[0]); o[5] = (short)f2b(b[1]);
  o[6] = (short)f2b(b[2]); o[7] = (short)f2b(b[3]);
  ((bfrag*)out)[i] = o;
}

// ---------------- kernel 2: W [K][N] fp32 -> Wt [N][K] bf16 (x3) ----------------
__global__ __launch_bounds__(256) void cvt_w_kernel(const float* __restrict__ W0,
                                                    const float* __restrict__ W1,
                                                    const float* __restrict__ W2,
                                                    uint16_t* __restrict__ Wt) {
  const float* W = blockIdx.z == 0 ? W0 : (blockIdx.z == 1 ? W1 : W2);
  uint16_t* out = Wt + (size_t)blockIdx.z * HIDDEN * HIDDEN;
  __shared__ float tile[64][65];
  int n0 = blockIdx.x * 64, k0 = blockIdx.y * 64;
  int t = threadIdx.x;
  int r = t >> 2, cq = (t & 3) * 16;
#pragma unroll
  for (int i = 0; i < 16; i += 4) {
    float4v v = *(const float4v*)&W[(size_t)(k0 + r) * HIDDEN + n0 + cq + i];
    tile[r][cq + i + 0] = v[0]; tile[r][cq + i + 1] = v[1];
    tile[r][cq + i + 2] = v[2]; tile[r][cq + i + 3] = v[3];
  }
  __syncthreads();
  bfrag o0, o1;
#pragma unroll
  for (int i = 0; i < 8; ++i) o0[i] = (short)f2b(tile[cq + i][r]);
#pragma unroll
  for (int i = 0; i < 8; ++i) o1[i] = (short)f2b(tile[cq + 8 + i][r]);
  *(bfrag*)&out[(size_t)(n0 + r) * HIDDEN + k0 + cq] = o0;
  *(bfrag*)&out[(size_t)(n0 + r) * HIDDEN + k0 + cq + 8] = o1;
}

// ---------------- kernel 3: QKV projection GEMM (m97 structure) ----------------
// C[m][n] = sum_k X[m][k] * Wt[n][k] + bias[n]; out bf16 [8192][1024]
__global__ __launch_bounds__(256) void gemm_qkv_kernel(
    const uint16_t* __restrict__ X, const uint16_t* __restrict__ Wt,
    const float* __restrict__ b0, const float* __restrict__ b1,
    const float* __restrict__ b2,
    uint16_t* __restrict__ Qo, uint16_t* __restrict__ Ko, uint16_t* __restrict__ Vo) {
  __shared__ uint16_t As[128 * 32];
  __shared__ uint16_t Bs[128 * 32];
  int which = blockIdx.z;
  const uint16_t* Wp = Wt + (size_t)which * HIDDEN * HIDDEN;
  const float* bias = which == 0 ? b0 : (which == 1 ? b1 : b2);
  uint16_t* out = which == 0 ? Qo : (which == 1 ? Ko : Vo);

  int m0 = blockIdx.x * 128, n0 = blockIdx.y * 128;
  int tid = threadIdx.x;
  int wave = tid >> 6, lane = tid & 63;
  int wm = wave >> 1, wn = wave & 1;       // 2x2 wave grid, 64x64 per wave
  int g = lane >> 4, c = lane & 15;
  int sr = lane >> 2;                       // staging: row within 16-row chunk
  int sc = (lane & 3) * 8;                  // staging: k offset (8 bf16 = 16B)

  cfrag acc[4][4];
#pragma unroll
  for (int i = 0; i < 4; ++i)
#pragma unroll
    for (int j = 0; j < 4; ++j) acc[i][j] = cfrag{0.f, 0.f, 0.f, 0.f};

  for (int kt = 0; kt < HIDDEN / 32; ++kt) {
    int kc = kt * 32 + sc;
#pragma unroll
    for (int i = 0; i < 2; ++i) {
      int rowA = (i * 4 + wave) * 16;  // wave-uniform
      gl_lds16(&X[(size_t)(m0 + rowA + sr) * HIDDEN + kc], &As[rowA * 32]);
      gl_lds16(&Wp[(size_t)(n0 + rowA + sr) * HIDDEN + kc], &Bs[rowA * 32]);
    }
    __syncthreads();  // vmcnt(0) drained before barrier -> LDS ready
    bfrag af[4], bf[4];
#pragma unroll
    for (int mt = 0; mt < 4; ++mt)
      af[mt] = *(const bfrag*)&As[(wm * 64 + mt * 16 + c) * 32 + g * 8];
#pragma unroll
    for (int nt = 0; nt < 4; ++nt)
      bf[nt] = *(const bfrag*)&Bs[(wn * 64 + nt * 16 + c) * 32 + g * 8];
#pragma unroll
    for (int mt = 0; mt < 4; ++mt)
#pragma unroll
      for (int nt = 0; nt < 4; ++nt)
        acc[mt][nt] = __builtin_amdgcn_mfma_f32_16x16x32_bf16(af[mt], bf[nt],
                                                              acc[mt][nt], 0, 0, 0);
    __syncthreads();  // all waves done with LDS before next stage
  }

#pragma unroll
  for (int nt = 0; nt < 4; ++nt) {
    int n = n0 + wn * 64 + nt * 16 + c;
    float bb = bias[n];
#pragma unroll
    for (int mt = 0; mt < 4; ++mt) {
      int mb = m0 + wm * 64 + mt * 16 + g * 4;
#pragma unroll
      for (int r = 0; r < 4; ++r)
        out[(size_t)(mb + r) * HIDDEN + n] = f2b(acc[mt][nt][r] + bb);
    }
  }
}

// ---------------- kernel 4: flash attention ----------------
// Q,K,V bf16 [8192][1024] (head h = cols h*64..h*64+63); out fp32 [8192][1024]
__global__ __launch_bounds__(256) void attn_kernel(
    const uint16_t* __restrict__ Q, const uint16_t* __restrict__ K,
    const uint16_t* __restrict__ V, float* __restrict__ out) {
  __shared__ uint16_t Vt[64][72];        // [d][kv], +8 pad vs bank conflicts
  __shared__ uint16_t Pl[4][16][72];     // per-wave P [qrow][kv], padded

  int qt = blockIdx.x, bh = blockIdx.y;
  int b = bh >> 4, h = bh & 15;
  int tid = threadIdx.x, wave = tid >> 6, lane = tid & 63;
  int g = lane >> 4, c = lane & 15;
  size_t rowb = (size_t)b * SEQ;
  int colb = h * HDIM;

  // Q fragments (A-frag: row = lane&15, k = g*8..g*8+7), held for all kv tiles
  int qrow = qt * 64 + wave * 16 + c;
  bfrag aq[2];
  aq[0] = *(const bfrag*)&Q[(rowb + qrow) * HIDDEN + colb + g * 8];
  aq[1] = *(const bfrag*)&Q[(rowb + qrow) * HIDDEN + colb + 32 + g * 8];

  float mr[4], lr[4];
  cfrag oacc[4];
#pragma unroll
  for (int r = 0; r < 4; ++r) { mr[r] = -INFINITY; lr[r] = 0.f; }
#pragma unroll
  for (int dt = 0; dt < 4; ++dt) oacc[dt] = cfrag{0.f, 0.f, 0.f, 0.f};

  int vr = tid >> 2;          // staging: kv row 0..63
  int dc = (tid & 3) * 16;    // staging: d col chunk

  for (int j0 = 0; j0 < SEQ; j0 += 64) {
    __syncthreads();  // prev PV reads done before Vt overwrite
    {
      const uint16_t* vp = &V[(rowb + j0 + vr) * HIDDEN + colb + dc];
      bfrag v0 = *(const bfrag*)vp;
      bfrag v1 = *(const bfrag*)(vp + 8);
#pragma unroll
      for (int i = 0; i < 8; ++i) Vt[dc + i][vr] = (uint16_t)v0[i];
#pragma unroll
      for (int i = 0; i < 8; ++i) Vt[dc + 8 + i][vr] = (uint16_t)v1[i];
    }
    __syncthreads();

    // S = Q @ K^T  (K B-frag straight from global; K tile is L2-resident)
    cfrag s[4];
#pragma unroll
    for (int nt = 0; nt < 4; ++nt) s[nt] = cfrag{0.f, 0.f, 0.f, 0.f};
#pragma unroll
    for (int kb = 0; kb < 2; ++kb) {
#pragma unroll
      for (int nt = 0; nt < 4; ++nt) {
        bfrag bk = *(const bfrag*)&K[(rowb + j0 + nt * 16 + c) * HIDDEN +
                                     colb + kb * 32 + g * 8];
        s[nt] = __builtin_amdgcn_mfma_f32_16x16x32_bf16(aq[kb], bk, s[nt], 0, 0, 0);
      }
    }

    // online softmax; row = g*4+r, cols spread over 16-lane group x 4 tiles
#pragma unroll
    for (int r = 0; r < 4; ++r) {
      float s0 = s[0][r] * 0.125f, s1 = s[1][r] * 0.125f,
            s2 = s[2][r] * 0.125f, s3 = s[3][r] * 0.125f;
      float mx = fmaxf(fmaxf(s0, s1), fmaxf(s2, s3));
#pragma unroll
      for (int off = 1; off < 16; off <<= 1)
        mx = fmaxf(mx, __shfl_xor(mx, off, 64));
      float mnew = fmaxf(mr[r], mx);
      float alpha = __expf(mr[r] - mnew);   // exp(-inf)=0 on first tile
      float p0 = __expf(s0 - mnew), p1 = __expf(s1 - mnew),
            p2 = __expf(s2 - mnew), p3 = __expf(s3 - mnew);
      float ps = p0 + p1 + p2 + p3;
#pragma unroll
      for (int off = 1; off < 16; off <<= 1)
        ps += __shfl_xor(ps, off, 64);
      lr[r] = lr[r] * alpha + ps;
      mr[r] = mnew;
#pragma unroll
      for (int dt = 0; dt < 4; ++dt) oacc[dt][r] *= alpha;
      int prow = g * 4 + r;
      Pl[wave][prow][c]      = f2b(p0);
      Pl[wave][prow][16 + c] = f2b(p1);
      Pl[wave][prow][32 + c] = f2b(p2);
      Pl[wave][prow][48 + c] = f2b(p3);
    }
    __syncthreads();  // P visible (and Vt still valid)

    // PV: ctx += P @ V
#pragma unroll
    for (int kb = 0; kb < 2; ++kb) {
      bfrag ap = *(const bfrag*)&Pl[wave][c][kb * 32 + g * 8];
#pragma unroll
      for (int dt = 0; dt < 4; ++dt) {
        bfrag bv = *(const bfrag*)&Vt[dt * 16 + c][kb * 32 + g * 8];
        oacc[dt] = __builtin_amdgcn_mfma_f32_16x16x32_bf16(ap, bv, oacc[dt], 0, 0, 0);
      }
    }
  }

#pragma unroll
  for (int r = 0; r < 4; ++r) {
    float inv = 1.0f / lr[r];
    size_t orow = rowb + (size_t)qt * 64 + wave * 16 + g * 4 + r;
#pragma unroll
    for (int dt = 0; dt < 4; ++dt)
      out[orow * HIDDEN + colb + dt * 16 + c] = oacc[dt][r] * inv;
  }
}

extern "C" void kernel_launch(void* const* d_in, const int* in_sizes, int n_in,
                              void* d_out, int out_size, void* d_ws, size_t ws_size,
                              hipStream_t stream) {
  const float* x  = (const float*)d_in[0];
  const float* Wq = (const float*)d_in[1];
  const float* bq = (const float*)d_in[2];
  const float* Wk = (const float*)d_in[3];
  const float* bk = (const float*)d_in[4];
  const float* Wv = (const float*)d_in[5];
  const float* bv = (const float*)d_in[6];
  float* out = (float*)d_out;

  uint8_t* ws = (uint8_t*)d_ws;
  const size_t XB = 0;
  const size_t WT = XB + (size_t)MTOT * HIDDEN * 2;        // 16 MB
  const size_t QB = WT + (size_t)3 * HIDDEN * HIDDEN * 2;  // +6 MB
  const size_t KB = QB + (size_t)MTOT * HIDDEN * 2;
  const size_t VB = KB + (size_t)MTOT * HIDDEN * 2;        // total ~70 MB
  uint16_t* Xb = (uint16_t*)(ws + XB);
  uint16_t* Wt = (uint16_t*)(ws + WT);
  uint16_t* Qb = (uint16_t*)(ws + QB);
  uint16_t* Kb = (uint16_t*)(ws + KB);
  uint16_t* Vb = (uint16_t*)(ws + VB);

  cvt_x_kernel<<<dim3(MTOT * HIDDEN / 8 / 256), 256, 0, stream>>>(x, Xb,
                                                                  MTOT * HIDDEN / 8);
  cvt_w_kernel<<<dim3(16, 16, 3), 256, 0, stream>>>(Wq, Wk, Wv, Wt);
  gemm_qkv_kernel<<<dim3(64, 8, 3), 256, 0, stream>>>(Xb, Wt, bq, bk, bv, Qb, Kb, Vb);
  attn_kernel<<<dim3(32, 64), 256, 0, stream>>>(Qb, Kb, Vb, out);
}